// Round 10
// baseline (15.201 us; speedup 1.0000x reference)
//
#include <hip/hip_runtime.h>
#include <hip/hip_fp16.h>

// LocalAttention: B=1, H=8, S=2048, D=64, window +/-64 (129 positions), fp32 io.
// Barrier-light split-k MFMA design. 256 blocks (1/CU), 512 threads (8 waves):
// t = w&3 (q-tile), half = w>>2 (chunks 0-2 / 3-5 of the 192-row window).
// K is NOT staged: each wave loads its QK B-fragments straight from global
// (fp32, clamped rows) into registers up-front; QK starts as soon as chunk 0
// lands (in-order vmcnt queue pipelines chunks 1-2). P -> 3 per-wave LDS strips.
// V loads issue first, scatter to f16 V^T (384B stride + 16B-unit XOR swizzle)
// after QK; ONE __syncthreads; then PV (12 MFMA) + split-k combine (R6 verbatim).
// h = blockIdx.x & 7 keeps each head on one XCD's L2.

#define SEQ 2048
#define QB 64
#define PSTR 40          // P strip stride in halfs (80 B)

typedef _Float16 f16x8 __attribute__((ext_vector_type(8)));
typedef float    f32x4 __attribute__((ext_vector_type(4)));

__global__ __launch_bounds__(512) void local_attn(
    const float* __restrict__ q,
    const float* __restrict__ k,
    const float* __restrict__ v,
    float* __restrict__ out)
{
    __shared__ __align__(16) unsigned char VtB[64 * 384];    // 24576 B
    __shared__ __align__(16) _Float16      Pm[24][16 * PSTR];// 30720 B (8w x 3c)
    __shared__ __align__(16) float         Cmb[4][64][20];   // 20480 B

    const int tid  = threadIdx.x;
    const int lane = tid & 63;
    const int w    = tid >> 6;           // 0..7
    const int t    = w & 3;              // q-tile 0..3
    const int half = w >> 2;             // 0: chunks 0-2, 1: chunks 3-5
    const int l15  = lane & 15;
    const int l4   = lane >> 4;
    const int bx   = blockIdx.x;
    const int h     = bx & 7;            // head == XCD (round-robin dispatch)
    const int qbase = (bx >> 3) * QB;

    const float* qh = q + (size_t)h * SEQ * 64;
    const float* kh = k + (size_t)h * SEQ * 64;
    const float* vh = v + (size_t)h * SEQ * 64;

    // ---- V loads first (arrive during QK phase; scattered later)
    const int d4  = (tid & 15) << 2;     // 4 dims per thread
    const int vr0 = tid >> 4;            // rows vr0 + 32*it, it=0..5
    float4 vreg[6];
    #pragma unroll
    for (int it = 0; it < 6; ++it) {
        int g = qbase - 64 + vr0 + it * 32;
        g = g < 0 ? 0 : (g > SEQ - 1 ? SEQ - 1 : g);
        vreg[it] = *(const float4*)(vh + (size_t)g * 64 + d4);
    }

    // ---- Q loads
    const float* qrow = qh + (size_t)(qbase + t * 16 + l15) * 64 + l4 * 8;
    float4 q0 = *(const float4*)(qrow);
    float4 q1 = *(const float4*)(qrow + 4);
    float4 q2 = *(const float4*)(qrow + 32);
    float4 q3 = *(const float4*)(qrow + 36);

    // ---- K fragment loads, all issued up-front (clamped rows)
    float4 kreg[3][2][4];
    #pragma unroll
    for (int c = 0; c < 3; ++c) {
        #pragma unroll
        for (int t2 = 0; t2 < 2; ++t2) {
            const int r = (half * 3 + c) * 32 + t2 * 16 + l15;
            int g = qbase - 64 + r;
            g = g < 0 ? 0 : (g > SEQ - 1 ? SEQ - 1 : g);
            const float* kr = kh + (size_t)g * 64 + l4 * 8;
            kreg[c][t2][0] = *(const float4*)(kr);
            kreg[c][t2][1] = *(const float4*)(kr + 4);
            kreg[c][t2][2] = *(const float4*)(kr + 32);
            kreg[c][t2][3] = *(const float4*)(kr + 36);
        }
    }

    // ---- pack Q A-fragments (1/sqrt(64)=0.125 folded in)
    union uf { f16x8 v; _Float16 hh[8]; };
    uf A0, A1;
    A0.hh[0] = (_Float16)(q0.x * 0.125f); A0.hh[1] = (_Float16)(q0.y * 0.125f);
    A0.hh[2] = (_Float16)(q0.z * 0.125f); A0.hh[3] = (_Float16)(q0.w * 0.125f);
    A0.hh[4] = (_Float16)(q1.x * 0.125f); A0.hh[5] = (_Float16)(q1.y * 0.125f);
    A0.hh[6] = (_Float16)(q1.z * 0.125f); A0.hh[7] = (_Float16)(q1.w * 0.125f);
    A1.hh[0] = (_Float16)(q2.x * 0.125f); A1.hh[1] = (_Float16)(q2.y * 0.125f);
    A1.hh[2] = (_Float16)(q2.z * 0.125f); A1.hh[3] = (_Float16)(q2.w * 0.125f);
    A1.hh[4] = (_Float16)(q3.x * 0.125f); A1.hh[5] = (_Float16)(q3.y * 0.125f);
    A1.hh[6] = (_Float16)(q3.z * 0.125f); A1.hh[7] = (_Float16)(q3.w * 0.125f);

    // ---- QK phase: 3 chunks, consume kreg in issue order (pipelined drains)
    float rsum[4] = {0.f, 0.f, 0.f, 0.f};
    #pragma unroll
    for (int c = 0; c < 3; ++c) {
        _Float16* Pw = Pm[w * 3 + c];
        #pragma unroll
        for (int t2 = 0; t2 < 2; ++t2) {
            const int r = (half * 3 + c) * 32 + t2 * 16 + l15;
            uf b0, b1;
            #pragma unroll
            for (int j = 0; j < 4; ++j) {
                b0.hh[j]     = (_Float16)kreg[c][t2][0][j];
                b0.hh[j + 4] = (_Float16)kreg[c][t2][1][j];
                b1.hh[j]     = (_Float16)kreg[c][t2][2][j];
                b1.hh[j + 4] = (_Float16)kreg[c][t2][3][j];
            }
            f32x4 cacc = {0.f, 0.f, 0.f, 0.f};
            cacc = __builtin_amdgcn_mfma_f32_16x16x32_f16(A0.v, b0.v, cacc, 0, 0, 0);
            cacc = __builtin_amdgcn_mfma_f32_16x16x32_f16(A1.v, b1.v, cacc, 0, 0, 0);
            const int g  = qbase - 64 + r;
            const bool gv = (g >= 0) & (g < SEQ);
            #pragma unroll
            for (int j = 0; j < 4; ++j) {
                const int qg = qbase + t * 16 + l4 * 4 + j;   // global query (C row)
                const bool valid = gv && (g >= qg - 64) && (g <= qg + 64);
                const float e = valid ? __expf(cacc[j]) : 0.f;
                rsum[j] += e;
                Pw[(l4 * 4 + j) * PSTR + t2 * 16 + l15] = (_Float16)e;
            }
        }
    }

    // ---- V scatter to f16 V^T (data arrived long ago), then the ONE barrier
    #pragma unroll
    for (int it = 0; it < 6; ++it) {
        const int r = vr0 + it * 32;
        #pragma unroll
        for (int i2 = 0; i2 < 4; ++i2) {
            const int d = d4 + i2;
            const int u = (r >> 3) ^ (d & 7);
            *(_Float16*)&VtB[d * 384 + (u << 4) + (r & 7) * 2] =
                (_Float16)vreg[it][i2];
        }
    }
    __syncthreads();   // drains LDS queue: Pm strips + VtB all visible

    // ---- PV phase: 3 chunks x 4 dtiles, pure LDS + MFMA
    f32x4 o[4];
    #pragma unroll
    for (int dt = 0; dt < 4; ++dt) o[dt] = (f32x4){0.f, 0.f, 0.f, 0.f};
    #pragma unroll
    for (int c = 0; c < 3; ++c) {
        const int r0 = (half * 3 + c) * 32;
        f16x8 a = *(const f16x8*)&Pm[w * 3 + c][l15 * PSTR + l4 * 8];
        #pragma unroll
        for (int dt = 0; dt < 4; ++dt) {
            const int dim = dt * 16 + l15;
            const int u   = ((r0 + l4 * 8) >> 3) ^ (dim & 7);
            f16x8 bb = *(const f16x8*)&VtB[dim * 384 + (u << 4)];
            o[dt] = __builtin_amdgcn_mfma_f32_16x16x32_f16(a, bb, o[dt], 0, 0, 0);
        }
    }

    // ---- split-k combine: half-1 waves publish partials; half-0 waves merge
    if (half == 1) {
        #pragma unroll
        for (int dt = 0; dt < 4; ++dt)
            *(f32x4*)&Cmb[t][lane][dt * 4] = o[dt];
        f32x4 pr = {rsum[0], rsum[1], rsum[2], rsum[3]};
        *(f32x4*)&Cmb[t][lane][16] = pr;
    }
    __syncthreads();
    if (half == 0) {
        #pragma unroll
        for (int dt = 0; dt < 4; ++dt) {
            f32x4 p = *(const f32x4*)&Cmb[t][lane][dt * 4];
            o[dt] += p;
        }
        f32x4 pr = *(const f32x4*)&Cmb[t][lane][16];

        #pragma unroll
        for (int j = 0; j < 4; ++j) {
            float l = rsum[j] + pr[j];
            l += __shfl_xor(l, 1, 64);
            l += __shfl_xor(l, 2, 64);
            l += __shfl_xor(l, 4, 64);
            l += __shfl_xor(l, 8, 64);
            const float inv = 1.0f / l;
            const int qg = qbase + t * 16 + l4 * 4 + j;
            #pragma unroll
            for (int dt = 0; dt < 4; ++dt)
                out[((size_t)h * SEQ + qg) * 64 + dt * 16 + l15] = o[dt][j] * inv;
        }
    }
}

extern "C" void kernel_launch(void* const* d_in, const int* in_sizes, int n_in,
                              void* d_out, int out_size, void* d_ws, size_t ws_size,
                              hipStream_t stream)
{
    const float* q = (const float*)d_in[0];
    const float* k = (const float*)d_in[1];
    const float* v = (const float*)d_in[2];
    float* out = (float*)d_out;

    // 256 blocks = 1 per CU; low 3 bits = head -> one head per XCD (L2 locality)
    local_attn<<<256, 512, 0, stream>>>(q, k, v, out);
}

// Round 11
// 11.482 us; speedup vs baseline: 1.3239x; 1.3239x over previous
//
#include <hip/hip_runtime.h>
#include <hip/hip_fp16.h>

// LocalAttention: B=1, H=8, S=2048, D=64, window +/-64 (129 positions), fp32 io.
// R6 split-k MFMA structure (best: 11.8us) with T14 async-split staging:
// all 12 K/V float4 loads issued to registers FIRST (clamped rows, no branch),
// then cvt+scatter to LDS -> one exposed HBM round-trip instead of ~6.
// 256 blocks (1/CU), 512 threads (8 waves): t = w&3 (q-tile), half = w>>2
// (chunks 0-2 / 3-5 of 192 staged rows). Per 32-row chunk: QK (2 tiles x 2 MFMA)
// -> exp -> wave-local P strip -> PV (4 dtiles x 1 MFMA); P ordering is
// same-wave DS program order. K row-major f16 LDS (stride 72h), V^T f16 LDS
// (384B stride + 16B-unit XOR swizzle), Q frags from global.
// h = blockIdx.x & 7 keeps each head on one XCD's L2. Split-k combine via LDS.

#define SEQ 2048
#define QB 64
#define ROWS 192
#define PSTR 40          // P strip stride in halfs (80 B)

typedef _Float16 f16x8 __attribute__((ext_vector_type(8)));
typedef float    f32x4 __attribute__((ext_vector_type(4)));

static __device__ __forceinline__ ushort4 pack4(float4 f) {
    union { _Float16 h[4]; ushort4 u; } p;
    p.h[0] = (_Float16)f.x;
    p.h[1] = (_Float16)f.y;
    p.h[2] = (_Float16)f.z;
    p.h[3] = (_Float16)f.w;
    return p.u;
}

__global__ __launch_bounds__(512) void local_attn(
    const float* __restrict__ q,
    const float* __restrict__ k,
    const float* __restrict__ v,
    float* __restrict__ out)
{
    __shared__ __align__(16) _Float16      Kl[ROWS * 72];     // 27648 B
    __shared__ __align__(16) unsigned char VtB[64 * 384];     // 24576 B
    __shared__ __align__(16) _Float16      Pm[8][16 * PSTR];  // 10240 B
    __shared__ __align__(16) float         Cmb[4][64][20];    // 20480 B

    const int tid  = threadIdx.x;
    const int lane = tid & 63;
    const int w    = tid >> 6;           // 0..7
    const int t    = w & 3;              // q-tile 0..3
    const int half = w >> 2;             // 0: chunks 0-2, 1: chunks 3-5
    const int l15  = lane & 15;
    const int l4   = lane >> 4;
    const int bx   = blockIdx.x;
    const int h     = bx & 7;            // head == XCD (round-robin dispatch)
    const int qbase = (bx >> 3) * QB;

    const float* qh = q + (size_t)h * SEQ * 64;
    const float* kh = k + (size_t)h * SEQ * 64;
    const float* vh = v + (size_t)h * SEQ * 64;

    // ---- Q loads
    const float* qrow = qh + (size_t)(qbase + t * 16 + l15) * 64 + l4 * 8;
    float4 q0 = *(const float4*)(qrow);
    float4 q1 = *(const float4*)(qrow + 4);
    float4 q2 = *(const float4*)(qrow + 32);
    float4 q3 = *(const float4*)(qrow + 36);

    // ---- staging phase A: issue ALL 12 K/V loads (clamped rows, no branches)
    const int d4  = (tid & 15) << 2;     // fixed dims 0,4,...,60
    const int lr0 = tid >> 4;            // 0..31; rows advance by 32/iter
    float4 kv[6], vv[6];
    #pragma unroll
    for (int it = 0; it < 6; ++it) {
        int g = qbase - 64 + lr0 + it * 32;
        g = g < 0 ? 0 : (g > SEQ - 1 ? SEQ - 1 : g);
        const float* base = kh + (size_t)g * 64 + d4;
        kv[it] = *(const float4*)(base);
        vv[it] = *(const float4*)(vh + (size_t)g * 64 + d4);
    }

    // ---- pack Q A-fragments (1/sqrt(64)=0.125 folded in) while loads fly
    union uf { f16x8 v; _Float16 hh[8]; };
    uf A0, A1;
    A0.hh[0] = (_Float16)(q0.x * 0.125f); A0.hh[1] = (_Float16)(q0.y * 0.125f);
    A0.hh[2] = (_Float16)(q0.z * 0.125f); A0.hh[3] = (_Float16)(q0.w * 0.125f);
    A0.hh[4] = (_Float16)(q1.x * 0.125f); A0.hh[5] = (_Float16)(q1.y * 0.125f);
    A0.hh[6] = (_Float16)(q1.z * 0.125f); A0.hh[7] = (_Float16)(q1.w * 0.125f);
    A1.hh[0] = (_Float16)(q2.x * 0.125f); A1.hh[1] = (_Float16)(q2.y * 0.125f);
    A1.hh[2] = (_Float16)(q2.z * 0.125f); A1.hh[3] = (_Float16)(q2.w * 0.125f);
    A1.hh[4] = (_Float16)(q3.x * 0.125f); A1.hh[5] = (_Float16)(q3.y * 0.125f);
    A1.hh[6] = (_Float16)(q3.z * 0.125f); A1.hh[7] = (_Float16)(q3.w * 0.125f);

    // ---- staging phase B: convert + scatter to LDS (loads drain in order)
    #pragma unroll
    for (int it = 0; it < 6; ++it) {
        const int lr = lr0 + it * 32;
        *(ushort4*)&Kl[lr * 72 + d4] = pack4(kv[it]);
        #pragma unroll
        for (int i2 = 0; i2 < 4; ++i2) {
            const int d = d4 + i2;
            const int u = (lr >> 3) ^ (d & 7);
            *(_Float16*)&VtB[d * 384 + (u << 4) + (lr & 7) * 2] =
                (_Float16)vv[it][i2];
        }
    }
    __syncthreads();

    // ---- main loop: wave-private, 3 chunks per wave
    _Float16* Pw = Pm[w];
    float rsum[4] = {0.f, 0.f, 0.f, 0.f};
    f32x4 o[4];
    #pragma unroll
    for (int dt = 0; dt < 4; ++dt) o[dt] = (f32x4){0.f, 0.f, 0.f, 0.f};

    #pragma unroll
    for (int c = 0; c < 3; ++c) {
        const int r0 = (half * 3 + c) * 32;

        // QK^T for this 32-row chunk: 2 tiles
        #pragma unroll
        for (int t2 = 0; t2 < 2; ++t2) {
            const int r = r0 + t2 * 16 + l15;          // staged row (C col)
            f16x8 b0 = *(const f16x8*)&Kl[r * 72 + l4 * 8];
            f16x8 b1 = *(const f16x8*)&Kl[r * 72 + 32 + l4 * 8];
            f32x4 cacc = {0.f, 0.f, 0.f, 0.f};
            cacc = __builtin_amdgcn_mfma_f32_16x16x32_f16(A0.v, b0, cacc, 0, 0, 0);
            cacc = __builtin_amdgcn_mfma_f32_16x16x32_f16(A1.v, b1, cacc, 0, 0, 0);
            const int g  = qbase - 64 + r;
            const bool gv = (g >= 0) & (g < SEQ);
            #pragma unroll
            for (int j = 0; j < 4; ++j) {
                const int qg = qbase + t * 16 + l4 * 4 + j;   // global query (C row)
                const bool valid = gv && (g >= qg - 64) && (g <= qg + 64);
                const float e = valid ? __expf(cacc[j]) : 0.f;
                rsum[j] += e;
                Pw[(l4 * 4 + j) * PSTR + t2 * 16 + l15] = (_Float16)e;
            }
        }

        // same-wave DS order; drain so P reads see the writes
        asm volatile("s_waitcnt lgkmcnt(0)" ::: "memory");

        // PV: A = P chunk (lane l15 = query), B = V^T (lane l15 = dim)
        f16x8 a = *(const f16x8*)&Pw[l15 * PSTR + l4 * 8];
        #pragma unroll
        for (int dt = 0; dt < 4; ++dt) {
            const int dim = dt * 16 + l15;
            const int u   = ((r0 + l4 * 8) >> 3) ^ (dim & 7);
            f16x8 bb = *(const f16x8*)&VtB[dim * 384 + (u << 4)];
            o[dt] = __builtin_amdgcn_mfma_f32_16x16x32_f16(a, bb, o[dt], 0, 0, 0);
        }
    }

    // ---- split-k combine: half-1 waves publish partials; half-0 waves merge
    if (half == 1) {
        #pragma unroll
        for (int dt = 0; dt < 4; ++dt)
            *(f32x4*)&Cmb[t][lane][dt * 4] = o[dt];
        f32x4 pr = {rsum[0], rsum[1], rsum[2], rsum[3]};
        *(f32x4*)&Cmb[t][lane][16] = pr;
    }
    __syncthreads();
    if (half == 0) {
        #pragma unroll
        for (int dt = 0; dt < 4; ++dt) {
            f32x4 p = *(const f32x4*)&Cmb[t][lane][dt * 4];
            o[dt] += p;
        }
        f32x4 pr = *(const f32x4*)&Cmb[t][lane][16];

        #pragma unroll
        for (int j = 0; j < 4; ++j) {
            float l = rsum[j] + pr[j];
            l += __shfl_xor(l, 1, 64);
            l += __shfl_xor(l, 2, 64);
            l += __shfl_xor(l, 4, 64);
            l += __shfl_xor(l, 8, 64);
            const float inv = 1.0f / l;
            const int qg = qbase + t * 16 + l4 * 4 + j;
            #pragma unroll
            for (int dt = 0; dt < 4; ++dt)
                out[((size_t)h * SEQ + qg) * 64 + dt * 16 + l15] = o[dt][j] * inv;
        }
    }
}

extern "C" void kernel_launch(void* const* d_in, const int* in_sizes, int n_in,
                              void* d_out, int out_size, void* d_ws, size_t ws_size,
                              hipStream_t stream)
{
    const float* q = (const float*)d_in[0];
    const float* k = (const float*)d_in[1];
    const float* v = (const float*)d_in[2];
    float* out = (float*)d_out;

    // 256 blocks = 1 per CU; low 3 bits = head -> one head per XCD (L2 locality)
    local_attn<<<256, 512, 0, stream>>>(q, k, v, out);
}